// Round 7
// baseline (201.687 us; speedup 1.0000x reference)
//
#include <hip/hip_runtime.h>
#include <math.h>

static constexpr int BB  = 4;
static constexpr int HH  = 1024;
static constexpr int WW  = 1024;
static constexpr int HWP = HH * WW;       // 1<<20
static constexpr int NPIX = BB * HWP;     // 4<<20
static constexpr int WPR = WW / 64;       // 16 words per image row
static constexpr int PW  = HWP / 64;      // 16384 words per image bitplane
static constexpr int ROUNDS = 6;

// fused-stencil tile: 64 wide x 16 tall output (TY=16 -> 27.9 KB LDS -> 5 blocks/CU)
static constexpr int TX = 64, TY = 16;
// LDS region shapes (rows x cols):
//   gray  : 24 x 72  (y0-4..y0+19 reflected, x0-4..x0+67 reflected)   -> array A
//   hblur : 24 x 68  (cols x0-2..x0+65)                               -> array B
//   vblur : 20 x 68  (rows y0-2..y0+17)                               -> array A (gray dead)
//   mag   : 18 x 66  (rows y0-1..y0+16, cols x0-1..x0+64)             -> array B (hblur dead)
//   dirp  : 16 x 64  center only                                       -> array P (u8)
static constexpr int GH = 24,  GW = 72;
static constexpr int HBH = 24, HBW = 68;
static constexpr int VBH = 20, VBW = 68;
static constexpr int MGH = 18, MGW = 66;

__device__ __forceinline__ int reflect_idx(int i, int n) {
    i = (i < 0) ? -i : i;                 // jnp.pad mode='reflect': -1 -> 1
    return (i >= n) ? (2 * n - 2 - i) : i;
}

// ---------- fused: gray -> hblur -> vblur -> sobel/mag -> dir -> NMS -> ballot ----------
__global__ void __launch_bounds__(256) k_front(const float* __restrict__ x,
                                               float* __restrict__ out0,
                                               float* __restrict__ out1,
                                               unsigned long long* __restrict__ weakP,
                                               unsigned long long* __restrict__ strongP,
                                               int* __restrict__ flags,
                                               double w0, double w1, double w2) {
    __shared__ double A[GH * GW];         // gray, then vblur
    __shared__ double B[HBH * HBW];       // hblur, then mag
    __shared__ unsigned char P[TY * TX];  // quantized direction, center pixels

    const int tid = threadIdx.x;
    const int x0  = blockIdx.x * TX;
    const int y0  = blockIdx.y * TY;
    const int b   = blockIdx.z;
    const float* base = x + (size_t)b * 3u * HWP;

    if (blockIdx.x == 0 && blockIdx.y == 0 && b == 0 && tid <= ROUNDS)
        flags[tid] = (tid == 0);          // seed flood-fill round flags

    // S1: grayscale into A (rows/cols pre-reflected so later reads are raw)
    for (int idx = tid; idx < GH * GW; idx += 256) {
        int r = idx / GW, c = idx - r * GW;
        int gyr = reflect_idx(y0 + r - 4, HH);
        int gxr = reflect_idx(x0 + c - 4, WW);
        const float* rp = base + (size_t)gyr * WW;
        double rr = (double)rp[gxr];
        double gg = (double)rp[HWP + gxr];
        double bb = (double)rp[2 * HWP + gxr];
        A[idx] = rr * 0.299 + gg * 0.587 + bb * 0.114;
    }
    __syncthreads();

    // S2: hblur into B (gray slot col j = c + d + 2, d = -2..2 -> j = c..c+4)
    for (int idx = tid; idx < HBH * HBW; idx += 256) {
        int r = idx / HBW, c = idx - r * HBW;
        const double* g = &A[r * GW + c];
        double s;
        s  = w0 * g[0];
        s += w1 * g[1];
        s += w2 * g[2];
        s += w1 * g[3];
        s += w0 * g[4];
        B[idx] = s;
    }
    __syncthreads();

    // S3: vblur into A (hblur slot rows r..r+4 = gy-2..gy+2, pre-reflected)
    for (int idx = tid; idx < VBH * VBW; idx += 256) {
        int r = idx / VBW, c = idx - r * VBW;
        const double* h = &B[r * HBW + c];
        double s;
        s  = w0 * h[0];
        s += w1 * h[1 * HBW];
        s += w2 * h[2 * HBW];
        s += w1 * h[3 * HBW];
        s += w0 * h[4 * HBW];
        A[idx] = s;
    }
    __syncthreads();

    // S4: sobel magnitude into B (0 outside image = NMS zero pad) + dir bytes for center
    for (int idx = tid; idx < MGH * MGW; idx += 256) {
        int r = idx / MGW, c = idx - r * MGW;
        int gy = y0 + r - 1, gx = x0 + c - 1;
        double mg = 0.0;
        if (gy >= 0 && gy < HH && gx >= 0 && gx < WW) {
            int ym = gy > 0 ? gy - 1 : 0, yp = gy < HH - 1 ? gy + 1 : HH - 1;
            int xm = gx > 0 ? gx - 1 : 0, xp = gx < WW - 1 ? gx + 1 : WW - 1;
            auto BL = [&](int yy, int xx) -> double {
                return A[(yy - y0 + 2) * VBW + (xx - x0 + 2)];
            };
            double b00 = BL(ym, xm), b01 = BL(ym, gx), b02 = BL(ym, xp);
            double b10 = BL(gy, xm),                   b12 = BL(gy, xp);
            double b20 = BL(yp, xm), b21 = BL(yp, gx), b22 = BL(yp, xp);
            double gxv = -b00 + b02 - 2.0 * b10 + 2.0 * b12 - b20 + b22;
            double gyv = -b00 - 2.0 * b01 - b02 + b20 + 2.0 * b21 + b22;
            mg = sqrt(gxv * gxv + gyv * gyv + 1e-6);
            if (r >= 1 && r < TY + 1 && c >= 1 && c < TX + 1) {
                // octant classification == round(atan2(gy,gx)*4/pi) mod 8, boundary-exact
                double ax = fabs(gxv), ay = fabs(gyv);
                int p;
                if (ay < 0.41421356237309503 * ax)       // tan(22.5deg)
                    p = (gxv >= 0.0) ? 0 : 4;
                else if (ay < 2.4142135623730951 * ax)   // tan(67.5deg)
                    p = (gyv >= 0.0) ? ((gxv >= 0.0) ? 1 : 3)
                                     : ((gxv >= 0.0) ? 7 : 5);
                else
                    p = (gyv >= 0.0) ? 2 : 6;
                P[(r - 1) * TX + (c - 1)] = (unsigned char)p;
            }
        }
        B[r * MGW + c] = mg;
    }
    __syncthreads();

    // S5: NMS + thresholds + ballot (one wave = one 64px row-word) + out1 init (strong)
    for (int k = 0; k < (TX * TY) / 256; ++k) {
        int idx = k * 256 + tid;
        int r = idx >> 6, c = idx & 63;
        double ctr = B[(r + 1) * MGW + (c + 1)];
        int p = P[idx];
        int dr = ((425   >> (2 * p)) & 3) - 1;
        int dc = ((36890 >> (2 * p)) & 3) - 1;
        double mp = B[(r + 1 + dr) * MGW + (c + 1 + dc)];
        double mn = B[(r + 1 - dr) * MGW + (c + 1 - dc)];
        bool ismax = ((ctr - mp) > 0.0) && ((ctr - mn) > 0.0);
        double sm = ismax ? ctr : 0.0;
        size_t gidx = (size_t)b * HWP + (size_t)(y0 + r) * WW + (x0 + c);
        out0[gidx] = (float)sm;
        bool strong = (sm > 0.2);
        bool weak   = (sm > 0.1) && !strong;
        out1[gidx] = strong ? 1.0f : 0.0f;    // pre-hysteresis edges; k_pass refines
        unsigned long long wb = __ballot(weak);
        unsigned long long sb = __ballot(strong);
        if ((tid & 63) == 0) {
            int word = (y0 + r) * WPR + (x0 >> 6);
            weakP[(size_t)b * PW + word]   = wb;
            strongP[(size_t)b * PW + word] = sb;
        }
    }
}

// ---------------- hysteresis: bitplane flood fill, full-height column strips ----------------
__device__ __forceinline__ unsigned long long ks_fill(unsigned long long g, unsigned long long p) {
    unsigned long long q;
    q = p;        g |= q & (g << 1);
    q &= q << 1;  g |= q & (g << 2);
    q &= q << 2;  g |= q & (g << 4);
    q &= q << 4;  g |= q & (g << 8);
    q &= q << 8;  g |= q & (g << 16);
    q &= q << 16; g |= q & (g << 32);
    q = p;        g |= q & (g >> 1);
    q &= q >> 1;  g |= q & (g >> 2);
    q &= q >> 2;  g |= q & (g >> 4);
    q &= q >> 4;  g |= q & (g >> 8);
    q &= q >> 8;  g |= q & (g >> 16);
    q &= q >> 16; g |= q & (g >> 32);
    return g;
}

__global__ void __launch_bounds__(256) k_pass(const unsigned long long* __restrict__ weakP,
                                              unsigned long long* __restrict__ strongP,
                                              float* __restrict__ out1,
                                              int* __restrict__ flags, int rr) {
    __shared__ unsigned long long sp[HH + 2];   // spread-form strong rows (+zero halo)
    __shared__ int s_changed;

    if (flags[rr - 1] == 0) return;             // previous round globally quiet

    const int tid = threadIdx.x;
    const int blk = blockIdx.x;                 // 64 blocks: b(2b) | tx(4b); strip 64w x 1024h
    const int b  = blk >> 4;
    const int tx = blk & 15;
    const unsigned long long* wp = weakP + (size_t)b * PW;
    unsigned long long* spl      = strongP + (size_t)b * PW;
    const int r0 = tid * 4;

    unsigned long long w[4], s[4], ho[4];
    for (int i = 0; i < 4; ++i) {
        int row = r0 + i, wi = row * WPR + tx;
        w[i] = wp[wi];
        s[i] = spl[wi];
        unsigned long long h = 0;               // static horizontal halo from adjacent strips
        if (tx > 0)       h |= spl[wi - 1] >> 63;
        if (tx < WPR - 1) h |= spl[wi + 1] << 63;
        ho[i] = h;
        sp[row + 1] = (s[i] << 1) | s[i] | (s[i] >> 1) | h;
    }
    if (tid == 0) { sp[0] = 0; sp[HH + 1] = 0; }

    auto spread = [&](int i) -> unsigned long long {
        return (s[i] << 1) | s[i] | (s[i] >> 1) | ho[i];
    };

    int blockChanged = 0;
    for (;;) {
        __syncthreads();                        // (A) sp writes visible
        if (tid == 0) s_changed = 0;
        int ch = 0;
        unsigned long long up = sp[r0];         // down sweep (Gauss-Seidel in-thread)
        for (int i = 0; i < 4; ++i) {
            unsigned long long dn = (i < 3) ? spread(i + 1) : sp[r0 + 5];
            unsigned long long g = s[i] | (w[i] & (up | spread(i) | dn));
            g = ks_fill(g, w[i]);
            if (g != s[i]) { s[i] = g; ch = 1; }
            up = spread(i);
        }
        unsigned long long dn2 = sp[r0 + 5];    // up sweep
        for (int i = 3; i >= 0; --i) {
            unsigned long long upv = (i > 0) ? spread(i - 1) : sp[r0];
            unsigned long long g = s[i] | (w[i] & (upv | spread(i) | dn2));
            g = ks_fill(g, w[i]);
            if (g != s[i]) { s[i] = g; ch = 1; }
            dn2 = spread(i);
        }
        __syncthreads();                        // (B) reads done; reset visible
        if (ch) {
            for (int i = 0; i < 4; ++i) sp[r0 + i + 1] = spread(i);
            s_changed = 1;                      // benign race: all writers store 1
        }
        __syncthreads();                        // (C) writes + flag visible
        if (!s_changed) break;
        blockChanged = 1;
    }

    if (blockChanged) {
        for (int i = 0; i < 4; ++i) {
            spl[(r0 + i) * WPR + tx] = s[i];
            sp[r0 + i] = s[i];                  // raw rows for the out1 expansion below
        }
        if (tid == 0) atomicOr(&flags[rr], 1);  // device-scope by default
    }
    __syncthreads();                            // raw rows visible (blockChanged uniform)
    if (blockChanged) {
        float* ob = out1 + (size_t)b * HWP + (size_t)tx * 64;
        for (int i = tid; i < HH * 64; i += 256) {
            int row = i >> 6, lane = i & 63;    // wave: same row word, 64 consecutive floats
            ob[(size_t)row * WW + lane] = ((sp[row] >> lane) & 1ull) ? 1.0f : 0.0f;
        }
    }
}

extern "C" void kernel_launch(void* const* d_in, const int* in_sizes, int n_in,
                              void* d_out, int out_size, void* d_ws, size_t ws_size,
                              hipStream_t stream) {
    const float* x = (const float*)d_in[0];
    float* out0 = (float*)d_out;          // suppressed magnitude [4,1,1024,1024]
    float* out1 = out0 + NPIX;            // edges [4,1,1024,1024]

    // workspace: weakP | strongP | flags
    unsigned long long* weakP   = (unsigned long long*)d_ws;
    unsigned long long* strongP = weakP + (size_t)BB * PW;
    int* flags = (int*)(strongP + (size_t)BB * PW);

    // gaussian weights, f64 ops mirroring the reference
    double g0 = exp(-2.0), g1 = exp(-0.5), g2 = 1.0;
    double sum = (((g0 + g1) + g2) + g1) + g0;
    double w0 = g0 / sum, w1 = g1 / sum, w2 = g2 / sum;

    k_front<<<dim3(WW / TX, HH / TY, BB), dim3(256), 0, stream>>>(
        x, out0, out1, weakP, strongP, flags, w0, w1, w2);

    for (int r = 1; r <= ROUNDS; ++r)
        k_pass<<<dim3(BB * WPR), dim3(256), 0, stream>>>(weakP, strongP, out1, flags, r);
}

// Round 8
// 165.307 us; speedup vs baseline: 1.2201x; 1.2201x over previous
//
#include <hip/hip_runtime.h>
#include <math.h>

static constexpr int BB  = 4;
static constexpr int HH  = 1024;
static constexpr int WW  = 1024;
static constexpr int HWP = HH * WW;       // 1<<20
static constexpr int NPIX = BB * HWP;     // 4<<20
static constexpr int WPR = WW / 64;       // 16 words per image row
static constexpr int PW  = HWP / 64;      // 16384 words per image bitplane
static constexpr int ROUNDS = 6;

// fused-stencil tile: 64 wide x 16 tall output (TY=16 -> ~28 KB LDS -> 5 blocks/CU)
static constexpr int TX = 64, TY = 16;
static constexpr int GH = 24,  GW = 72;   // gray   (pre-reflected halo)
static constexpr int HBH = 24, HBW = 68;  // hblur
static constexpr int VBH = 20, VBW = 68;  // vblur
static constexpr int MGH = 18, MGW = 66;  // mag

__device__ __forceinline__ int reflect_idx(int i, int n) {
    i = (i < 0) ? -i : i;                 // jnp.pad mode='reflect': -1 -> 1
    return (i >= n) ? (2 * n - 2 - i) : i;
}

// ---------- fused: gray -> hblur -> vblur -> sobel/mag -> dir -> NMS -> ballot ----------
__global__ void __launch_bounds__(256) k_front(const float* __restrict__ x,
                                               float* __restrict__ out0,
                                               unsigned long long* __restrict__ weakP,
                                               unsigned long long* __restrict__ strongP,
                                               int* __restrict__ flags,
                                               double w0, double w1, double w2) {
    __shared__ double A[GH * GW];         // gray, then vblur
    __shared__ double B[HBH * HBW];       // hblur, then mag
    __shared__ unsigned char P[TY * TX];  // quantized direction, center pixels

    const int tid = threadIdx.x;
    const int x0  = blockIdx.x * TX;
    const int y0  = blockIdx.y * TY;
    const int b   = blockIdx.z;
    const float* base = x + (size_t)b * 3u * HWP;

    if (blockIdx.x == 0 && blockIdx.y == 0 && b == 0 && tid <= ROUNDS)
        flags[tid] = (tid == 0);          // seed flood-fill round flags

    // S1: grayscale into A (rows/cols pre-reflected so later reads are raw)
    for (int idx = tid; idx < GH * GW; idx += 256) {
        int r = idx / GW, c = idx - r * GW;
        int gyr = reflect_idx(y0 + r - 4, HH);
        int gxr = reflect_idx(x0 + c - 4, WW);
        const float* rp = base + (size_t)gyr * WW;
        double rr = (double)rp[gxr];
        double gg = (double)rp[HWP + gxr];
        double bb = (double)rp[2 * HWP + gxr];
        A[idx] = rr * 0.299 + gg * 0.587 + bb * 0.114;
    }
    __syncthreads();

    // S2: hblur into B
    for (int idx = tid; idx < HBH * HBW; idx += 256) {
        int r = idx / HBW, c = idx - r * HBW;
        const double* g = &A[r * GW + c];
        double s;
        s  = w0 * g[0];
        s += w1 * g[1];
        s += w2 * g[2];
        s += w1 * g[3];
        s += w0 * g[4];
        B[idx] = s;
    }
    __syncthreads();

    // S3: vblur into A
    for (int idx = tid; idx < VBH * VBW; idx += 256) {
        int r = idx / VBW, c = idx - r * VBW;
        const double* h = &B[r * HBW + c];
        double s;
        s  = w0 * h[0];
        s += w1 * h[1 * HBW];
        s += w2 * h[2 * HBW];
        s += w1 * h[3 * HBW];
        s += w0 * h[4 * HBW];
        A[idx] = s;
    }
    __syncthreads();

    // S4: sobel magnitude into B (0 outside image = NMS zero pad) + dir bytes for center
    for (int idx = tid; idx < MGH * MGW; idx += 256) {
        int r = idx / MGW, c = idx - r * MGW;
        int gy = y0 + r - 1, gx = x0 + c - 1;
        double mg = 0.0;
        if (gy >= 0 && gy < HH && gx >= 0 && gx < WW) {
            int ym = gy > 0 ? gy - 1 : 0, yp = gy < HH - 1 ? gy + 1 : HH - 1;
            int xm = gx > 0 ? gx - 1 : 0, xp = gx < WW - 1 ? gx + 1 : WW - 1;
            auto BL = [&](int yy, int xx) -> double {
                return A[(yy - y0 + 2) * VBW + (xx - x0 + 2)];
            };
            double b00 = BL(ym, xm), b01 = BL(ym, gx), b02 = BL(ym, xp);
            double b10 = BL(gy, xm),                   b12 = BL(gy, xp);
            double b20 = BL(yp, xm), b21 = BL(yp, gx), b22 = BL(yp, xp);
            double gxv = -b00 + b02 - 2.0 * b10 + 2.0 * b12 - b20 + b22;
            double gyv = -b00 - 2.0 * b01 - b02 + b20 + 2.0 * b21 + b22;
            mg = sqrt(gxv * gxv + gyv * gyv + 1e-6);
            if (r >= 1 && r < TY + 1 && c >= 1 && c < TX + 1) {
                // octant classification == round(atan2(gy,gx)*4/pi) mod 8, boundary-exact
                double ax = fabs(gxv), ay = fabs(gyv);
                int p;
                if (ay < 0.41421356237309503 * ax)       // tan(22.5deg)
                    p = (gxv >= 0.0) ? 0 : 4;
                else if (ay < 2.4142135623730951 * ax)   // tan(67.5deg)
                    p = (gyv >= 0.0) ? ((gxv >= 0.0) ? 1 : 3)
                                     : ((gxv >= 0.0) ? 7 : 5);
                else
                    p = (gyv >= 0.0) ? 2 : 6;
                P[(r - 1) * TX + (c - 1)] = (unsigned char)p;
            }
        }
        B[r * MGW + c] = mg;
    }
    __syncthreads();

    // S5: NMS + thresholds + ballot (one wave = one 64px row-word)
    for (int k = 0; k < (TX * TY) / 256; ++k) {
        int idx = k * 256 + tid;
        int r = idx >> 6, c = idx & 63;
        double ctr = B[(r + 1) * MGW + (c + 1)];
        int p = P[idx];
        int dr = ((425   >> (2 * p)) & 3) - 1;
        int dc = ((36890 >> (2 * p)) & 3) - 1;
        double mp = B[(r + 1 + dr) * MGW + (c + 1 + dc)];
        double mn = B[(r + 1 - dr) * MGW + (c + 1 - dc)];
        bool ismax = ((ctr - mp) > 0.0) && ((ctr - mn) > 0.0);
        double sm = ismax ? ctr : 0.0;
        out0[(size_t)b * HWP + (size_t)(y0 + r) * WW + (x0 + c)] = (float)sm;
        bool strong = (sm > 0.2);
        bool weak   = (sm > 0.1) && !strong;
        unsigned long long wb = __ballot(weak);
        unsigned long long sb = __ballot(strong);
        if ((tid & 63) == 0) {
            int word = (y0 + r) * WPR + (x0 >> 6);
            weakP[(size_t)b * PW + word]   = wb;
            strongP[(size_t)b * PW + word] = sb;
        }
    }
}

// ---------------- hysteresis: bitplane flood fill, full-height column strips ----------------
__device__ __forceinline__ unsigned long long ks_fill(unsigned long long g, unsigned long long p) {
    unsigned long long q;
    q = p;        g |= q & (g << 1);
    q &= q << 1;  g |= q & (g << 2);
    q &= q << 2;  g |= q & (g << 4);
    q &= q << 4;  g |= q & (g << 8);
    q &= q << 8;  g |= q & (g << 16);
    q &= q << 16; g |= q & (g << 32);
    q = p;        g |= q & (g >> 1);
    q &= q >> 1;  g |= q & (g >> 2);
    q &= q >> 2;  g |= q & (g >> 4);
    q &= q >> 4;  g |= q & (g >> 8);
    q &= q >> 8;  g |= q & (g >> 16);
    q &= q >> 16; g |= q & (g >> 32);
    return g;
}

__global__ void __launch_bounds__(256) k_pass(const unsigned long long* __restrict__ weakP,
                                              unsigned long long* __restrict__ strongP,
                                              int* __restrict__ flags, int rr) {
    __shared__ unsigned long long sp[HH + 2];   // spread-form strong rows (+zero halo)
    __shared__ int s_changed;

    if (flags[rr - 1] == 0) return;             // previous round globally quiet

    const int tid = threadIdx.x;
    const int blk = blockIdx.x;                 // 64 blocks: b(2b) | tx(4b); strip 64w x 1024h
    const int b  = blk >> 4;
    const int tx = blk & 15;
    const unsigned long long* wp = weakP + (size_t)b * PW;
    unsigned long long* spl      = strongP + (size_t)b * PW;
    const int r0 = tid * 4;

    unsigned long long w[4], s[4], ho[4];
    for (int i = 0; i < 4; ++i) {
        int row = r0 + i, wi = row * WPR + tx;
        w[i] = wp[wi];
        s[i] = spl[wi];
        unsigned long long h = 0;               // static horizontal halo from adjacent strips
        if (tx > 0)       h |= spl[wi - 1] >> 63;
        if (tx < WPR - 1) h |= spl[wi + 1] << 63;
        ho[i] = h;
        sp[row + 1] = (s[i] << 1) | s[i] | (s[i] >> 1) | h;
    }
    if (tid == 0) { sp[0] = 0; sp[HH + 1] = 0; s_changed = 0; }

    auto spread = [&](int i) -> unsigned long long {
        return (s[i] << 1) | s[i] | (s[i] >> 1) | ho[i];
    };

    // Gauss-Seidel across threads: publish sp[] immediately on change (monotone-safe;
    // exactness from the unchanged-fixed-point termination test below).
    int blockChanged = 0;
    for (;;) {
        __syncthreads();                        // (A) sp writes + s_changed reset visible
        int ch = 0;
        unsigned long long up = sp[r0];         // down sweep
        for (int i = 0; i < 4; ++i) {
            unsigned long long dn = (i < 3) ? spread(i + 1) : sp[r0 + 5];
            unsigned long long g = s[i] | (w[i] & (up | spread(i) | dn));
            g = ks_fill(g, w[i]);
            if (g != s[i]) { s[i] = g; ch = 1; sp[r0 + i + 1] = spread(i); }
            up = spread(i);
        }
        unsigned long long dn2 = sp[r0 + 5];    // up sweep
        for (int i = 3; i >= 0; --i) {
            unsigned long long upv = (i > 0) ? spread(i - 1) : sp[r0];
            unsigned long long g = s[i] | (w[i] & (upv | spread(i) | dn2));
            g = ks_fill(g, w[i]);
            if (g != s[i]) { s[i] = g; ch = 1; sp[r0 + i + 1] = spread(i); }
            dn2 = spread(i);
        }
        if (ch) s_changed = 1;                  // benign race: all writers store 1
        __syncthreads();                        // (B) all sets done
        int live = s_changed;
        __syncthreads();                        // (C) all reads done
        if (tid == 0) s_changed = 0;            // reset; visible after next (A)
        if (!live) break;
        blockChanged = 1;
    }

    if (blockChanged) {                         // uniform across block (from shared flag)
        for (int i = 0; i < 4; ++i) spl[(r0 + i) * WPR + tx] = s[i];
        if (tid == 0) atomicOr(&flags[rr], 1);  // device-scope by default
    }
}

__global__ void k_edges(const unsigned long long* __restrict__ strongP, float* __restrict__ out1) {
    int i = blockIdx.x * blockDim.x + threadIdx.x;
    if (i >= NPIX) return;
    out1[i] = ((strongP[i >> 6] >> (i & 63)) & 1ull) ? 1.0f : 0.0f;
}

extern "C" void kernel_launch(void* const* d_in, const int* in_sizes, int n_in,
                              void* d_out, int out_size, void* d_ws, size_t ws_size,
                              hipStream_t stream) {
    const float* x = (const float*)d_in[0];
    float* out0 = (float*)d_out;          // suppressed magnitude [4,1,1024,1024]
    float* out1 = out0 + NPIX;            // edges [4,1,1024,1024]

    // workspace: weakP | strongP | flags
    unsigned long long* weakP   = (unsigned long long*)d_ws;
    unsigned long long* strongP = weakP + (size_t)BB * PW;
    int* flags = (int*)(strongP + (size_t)BB * PW);

    // gaussian weights, f64 ops mirroring the reference
    double g0 = exp(-2.0), g1 = exp(-0.5), g2 = 1.0;
    double sum = (((g0 + g1) + g2) + g1) + g0;
    double w0 = g0 / sum, w1 = g1 / sum, w2 = g2 / sum;

    k_front<<<dim3(WW / TX, HH / TY, BB), dim3(256), 0, stream>>>(
        x, out0, weakP, strongP, flags, w0, w1, w2);

    for (int r = 1; r <= ROUNDS; ++r)
        k_pass<<<dim3(BB * WPR), dim3(256), 0, stream>>>(weakP, strongP, flags, r);

    k_edges<<<dim3(NPIX / 256), dim3(256), 0, stream>>>(strongP, out1);
}